// Round 7
// baseline (657.488 us; speedup 1.0000x reference)
//
#include <hip/hip_runtime.h>
#include <hip/hip_bf16.h>

#define E_N 8
#define D_DIM 1024
#define F_DIM 2048
#define T_N 2048
#define NSLOT 4096

typedef unsigned short u16;
typedef unsigned int u32;
typedef unsigned long long u64;
typedef float floatx4 __attribute__((ext_vector_type(4)));
typedef short bf16x8v __attribute__((ext_vector_type(8)));

// packed f32x2 -> bf16x2 (RNE), low half = first arg
__device__ __forceinline__ u32 cvtpk(float a, float b) {
    u32 r;
    asm("v_cvt_pk_bf16_f32 %0, %1, %2" : "=v"(r) : "v"(a), "v"(b));
    return r;
}

// async global->LDS, 16B per lane; LDS dest = wave-uniform base + lane*16
__device__ __forceinline__ void gll16(const void* g, void* l) {
    __builtin_amdgcn_global_load_lds((const __attribute__((address_space(1))) void*)g,
                                     (__attribute__((address_space(3))) void*)l, 16, 0, 0);
}

// ---------------- K1 Router: 8 blocks, 1 token/thread, per-block counts ----------------
__global__ __launch_bounds__(256) void router_kernel(const float* __restrict__ gl,
                                                     int4* __restrict__ tok_meta,
                                                     float* __restrict__ tok_w0,
                                                     int* __restrict__ bcnt) {
    __shared__ int scnt[E_N];
    const int tid = threadIdx.x, b = blockIdx.x;
    if (tid < E_N) scnt[tid] = 0;
    __syncthreads();
    const int t = b * 256 + tid;
    const float4* gp = (const float4*)(gl + (size_t)t * E_N);
    const float4 x0 = gp[0], x1 = gp[1];
    float l[E_N] = {x0.x, x0.y, x0.z, x0.w, x1.x, x1.y, x1.z, x1.w};
    int e0 = 0; float m0 = l[0];
#pragma unroll
    for (int e = 1; e < E_N; ++e) if (l[e] > m0) { m0 = l[e]; e0 = e; }
    int e1 = -1; float m1 = -1e30f;
#pragma unroll
    for (int e = 0; e < E_N; ++e) if (e != e0 && l[e] > m1) { m1 = l[e]; e1 = e; }
    const float p = __expf(m1 - m0);            // <= 1
    const float w0 = 1.0f / (1.0f + p);
    const int r0 = atomicAdd(&scnt[e0], 1);
    const int r1 = atomicAdd(&scnt[e1], 1);
    tok_meta[t] = make_int4(e0, e1, r0, r1);
    tok_w0[t] = w0;
    __syncthreads();
    if (tid < E_N) bcnt[b * E_N + tid] = scnt[tid];
}

// ---------------- K2 Finalize: global slots from bcnt prefix; zero out ----------------
__global__ __launch_bounds__(256) void finalize_kernel(
        const int4* __restrict__ tok_meta, const float* __restrict__ tok_w0,
        const int* __restrict__ bcnt,
        int* __restrict__ cnt, int* __restrict__ basep,
        int* __restrict__ slot_tok, float* __restrict__ slot_w,
        float* __restrict__ out) {
    const int b = blockIdx.x, tid = threadIdx.x;
    if (b < 8) {
        __shared__ int sb[64];
        if (tid < 64) sb[tid] = bcnt[tid];
        __syncthreads();
        int cntE[E_N], baseE[E_N];
        int s = 0;
#pragma unroll
        for (int e = 0; e < E_N; ++e) {
            int c = 0;
#pragma unroll
            for (int k = 0; k < 8; ++k) c += sb[k * E_N + e];
            cntE[e] = c; baseE[e] = s; s += c;
        }
        const int t = b * 256 + tid;
        const int4 mt = tok_meta[t];
        int o0 = baseE[mt.x], o1 = baseE[mt.y];
        for (int k = 0; k < b; ++k) { o0 += sb[k * E_N + mt.x]; o1 += sb[k * E_N + mt.y]; }
        const int s0 = o0 + mt.z, s1 = o1 + mt.w;
        const float w0 = tok_w0[t];
        slot_tok[s0] = t; slot_tok[s1] = t;
        slot_w[s0] = w0; slot_w[s1] = 1.0f - w0;
        if (b == 0 && tid < E_N) { cnt[tid] = cntE[tid]; basep[tid] = baseE[tid]; }
        if (b == 0) slot_tok[NSLOT + tid] = 0;     // pad the 128-row tile overhang
    } else {
        const int z = b - 8;                        // 512 blocks x 4096 f32 = 2M f32
        const float4 zq = {0.f, 0.f, 0.f, 0.f};
        float* op = out + (size_t)z * 4096 + tid * 16;
        *(float4*)op = zq; *(float4*)(op + 4) = zq;
        *(float4*)(op + 8) = zq; *(float4*)(op + 12) = zq;
    }
}

// ---------------- Grouped GEMM with fused f32->bf16 staging ----------------
// Tile 128x128, BK=64, 4 waves (2x2 of 64x64), 16x16x32 MFMA, 4x4 frags.
// LDS tiles [row][64] bf16 with 16B-slot XOR swizzle: byte = row*128 + ((slot^(row&7))<<4).
// G1: A = gather(X)[slot][D] f32 (cvt in staging), B = W1 [D][F] f32 (cvt in staging).
// G2: A = h bf16 (global_load_lds), B = W2 [F][D] f32 (cvt in staging).
template<bool G1>
__global__ __launch_bounds__(256, 3) void moe_gemm_kernel(
        const float* __restrict__ Xf, const u16* __restrict__ Ah,
        const float* __restrict__ Wf,
        const int* __restrict__ cnt, const int* __restrict__ basep,
        const int* __restrict__ slot_tok, const float* __restrict__ slot_w,
        u16* __restrict__ hout, float* __restrict__ out) {
    constexpr int KDIM = G1 ? D_DIM : F_DIM;
    constexpr int NDIM = G1 ? F_DIM : D_DIM;
    constexpr int KIT  = KDIM / 64;
    const int mt = blockIdx.x;
    const int nt = blockIdx.y;
    const int e  = blockIdx.z;
    const int cnt_e = cnt[e];
    if (mt * 128 >= cnt_e) return;
    const int m0 = basep[e] + mt * 128;
    const int vm = cnt_e - mt * 128;

    __shared__ __align__(16) u16 Alds[8192];
    __shared__ __align__(16) u16 Blds[8192];

    const int tid = threadIdx.x;
    const int wid = tid >> 6, lane = tid & 63;

    // ---- A staging setup
    const float* aF = nullptr; const u16* aH = nullptr;
    const int awm = tid >> 1, awk = (tid & 1) * 4;           // G1: row, slot base
    if constexpr (G1) {
        const int tok = slot_tok[m0 + awm];                  // padded -> safe
        aF = Xf + (size_t)tok * D_DIM + (tid & 1) * 32;
    } else {
        const int l3 = lane >> 3, l7 = lane & 7;
        aH = Ah + (size_t)(m0 + wid * 8 + l3) * KDIM + ((l7 ^ l3) << 3);
    }

    // ---- B staging setup: uniform row base + per-lane column
    const int n_loc = tid & 127;
    const int bh = __builtin_amdgcn_readfirstlane(tid >> 7); // wave-uniform half
    const float* bBase = Wf + (size_t)e * KDIM * NDIM + (size_t)(bh * 32) * NDIM + nt * 128;

    const int wm = (wid >> 1) * 64, wn = (wid & 1) * 64;
    const int lr = lane & 15, lq = lane >> 4, l7 = lane & 7;
    const int aoff = (wm + lr) * 64;
    const int boff = (wn + lr) * 64;
    const int sw0 = (lq ^ l7) << 3;
    const int sw1 = ((lq + 4) ^ l7) << 3;

    floatx4 acc[4][4];
    const floatx4 zero = {0.f, 0.f, 0.f, 0.f};
#pragma unroll
    for (int i = 0; i < 4; ++i)
#pragma unroll
        for (int j = 0; j < 4; ++j) acc[i][j] = zero;

    for (int kt = 0; kt < KIT; ++kt) {
        // ---- stage A
        if constexpr (G1) {
            float4 av[8];
#pragma unroll
            for (int i = 0; i < 8; ++i) av[i] = *(const float4*)(aF + i * 4);
            aF += 64;
            const float* f = (const float*)av;
#pragma unroll
            for (int c = 0; c < 4; ++c) {
                const u32 w0 = cvtpk(f[c * 8 + 0], f[c * 8 + 1]);
                const u32 w1 = cvtpk(f[c * 8 + 2], f[c * 8 + 3]);
                const u32 w2 = cvtpk(f[c * 8 + 4], f[c * 8 + 5]);
                const u32 w3 = cvtpk(f[c * 8 + 6], f[c * 8 + 7]);
                const int s = awk + c;
                *(uint4*)((char*)Alds + awm * 128 + ((s ^ (awm & 7)) << 4)) =
                    make_uint4(w0, w1, w2, w3);
            }
        } else {
#pragma unroll
            for (int c = 0; c < 4; ++c)
                gll16(aH + (size_t)(c * 32) * KDIM, (char*)Alds + c * 4096 + wid * 1024);
            aH += 64;
        }
        // ---- stage B (32 scalar f32 loads, coalesced along N; cvt pairs along K)
        {
            const size_t krow = (size_t)kt * 64 * NDIM;
#pragma unroll
            for (int q = 0; q < 4; ++q) {
                float v[8];
#pragma unroll
                for (int j = 0; j < 8; ++j)
                    v[j] = bBase[krow + (size_t)(q * 8 + j) * NDIM + n_loc];
                const u32 w0 = cvtpk(v[0], v[1]);
                const u32 w1 = cvtpk(v[2], v[3]);
                const u32 w2 = cvtpk(v[4], v[5]);
                const u32 w3 = cvtpk(v[6], v[7]);
                const int s = bh * 4 + q;
                *(uint4*)((char*)Blds + n_loc * 128 + ((s ^ (n_loc & 7)) << 4)) =
                    make_uint4(w0, w1, w2, w3);
            }
        }
        __syncthreads();   // drains vmcnt (gll16) + lgkm (ds_write)
#pragma unroll
        for (int ks = 0; ks < 2; ++ks) {
            const int sw = ks ? sw1 : sw0;
            bf16x8v af[4], bfv[4];
#pragma unroll
            for (int mi = 0; mi < 4; ++mi) af[mi]  = *(const bf16x8v*)&Alds[aoff + mi * 1024 + sw];
#pragma unroll
            for (int ni = 0; ni < 4; ++ni) bfv[ni] = *(const bf16x8v*)&Blds[boff + ni * 1024 + sw];
#pragma unroll
            for (int mi = 0; mi < 4; ++mi)
#pragma unroll
                for (int ni = 0; ni < 4; ++ni)
                    acc[mi][ni] = __builtin_amdgcn_mfma_f32_16x16x32_bf16(af[mi], bfv[ni], acc[mi][ni], 0, 0, 0);
        }
        __syncthreads();   // all frag reads done before next stage overwrites
    }

    if constexpr (G1) {
        // h = slot_w * silu(acc): weight folded so gemm2 can atomically combine
#pragma unroll
        for (int mi = 0; mi < 4; ++mi)
#pragma unroll
            for (int r = 0; r < 4; ++r) {
                const int rl = wm + mi * 16 + lq * 4 + r;
                if (rl < vm) {
                    const float w = slot_w[m0 + rl];
                    u16* hp = hout + (size_t)(m0 + rl) * F_DIM + nt * 128 + wn + lr;
#pragma unroll
                    for (int ni = 0; ni < 4; ++ni) {
                        const float v = acc[mi][ni][r];
                        union { float f; u32 u; } cv; cv.f = w * v / (1.0f + __expf(-v));
                        const u32 rr = cv.u + 0x7FFFu + ((cv.u >> 16) & 1u);
                        hp[ni * 16] = (u16)(rr >> 16);
                    }
                }
            }
    } else {
#pragma unroll
        for (int mi = 0; mi < 4; ++mi)
#pragma unroll
            for (int r = 0; r < 4; ++r) {
                const int rl = wm + mi * 16 + lq * 4 + r;
                if (rl < vm) {
                    const int tok = slot_tok[m0 + rl];
                    float* op = out + (size_t)tok * D_DIM + nt * 128 + wn + lr;
#pragma unroll
                    for (int ni = 0; ni < 4; ++ni) atomicAdd(&op[ni * 16], acc[mi][ni][r]);
                }
            }
    }
}

extern "C" void kernel_launch(void* const* d_in, const int* in_sizes, int n_in,
                              void* d_out, int out_size, void* d_ws, size_t ws_size,
                              hipStream_t stream) {
    const float* hidden = (const float*)d_in[0];   // [B,S,D] f32
    const float* gl     = (const float*)d_in[1];   // [T,E]   f32
    const float* W1     = (const float*)d_in[2];   // [E,D,F] f32
    const float* W2     = (const float*)d_in[3];   // [E,F,D] f32
    float* out = (float*)d_out;

    char* ws = (char*)d_ws;
    int*   cnt      = (int*)(ws + 0);
    int*   basep    = (int*)(ws + 64);
    int*   bcnt     = (int*)(ws + 128);
    int4*  tok_meta = (int4*)(ws + 512);               // 32 KB
    float* tok_w0   = (float*)(ws + 33280);            // 8 KB
    int*   slot_tok = (int*)(ws + 41472);              // 4352 ints (padded)
    float* slot_w   = (float*)(ws + 58880);            // 16 KB

    u16* h = (u16*)(ws + 131072);                      // [4224][F] bf16 = 17.3 MB (+slack)

    router_kernel<<<8, 256, 0, stream>>>(gl, tok_meta, tok_w0, bcnt);
    finalize_kernel<<<520, 256, 0, stream>>>(tok_meta, tok_w0, bcnt,
                                             cnt, basep, slot_tok, slot_w, out);
    moe_gemm_kernel<true><<<dim3(16, F_DIM / 128, E_N), 256, 0, stream>>>(
        hidden, nullptr, W1, cnt, basep, slot_tok, slot_w, h, nullptr);
    moe_gemm_kernel<false><<<dim3(16, D_DIM / 128, E_N), 256, 0, stream>>>(
        nullptr, h, W2, cnt, basep, slot_tok, slot_w, nullptr, out);
}